// Round 1
// baseline (4320.650 us; speedup 1.0000x reference)
//
#include <hip/hip_runtime.h>

#define NN 100000
#define NE 1600000

// ---------------- dtype detector: edge_index int64 vs int32 ----------------
// If data is int64 (values < 2^31), every odd 32-bit word is 0. For int32
// random node ids in [0,1e5), 64 consecutive odd words all-zero is impossible.
__global__ void detect_i64_k(const unsigned* __restrict__ ei, int* __restrict__ flag) {
    unsigned w = ei[2 * threadIdx.x + 1];
    unsigned long long b = __ballot(w == 0u);
    if (threadIdx.x == 0) *flag = (b == 0xFFFFFFFFFFFFFFFFull) ? 1 : 0;
}

// ---------------- degree / norm ----------------
__global__ void init_deg_k(float* __restrict__ deg) {
    int i = blockIdx.x * 256 + threadIdx.x;
    if (i < NN) deg[i] = 1.0f;   // self-loop contributes 1
}

__global__ void count_deg_k(const void* __restrict__ ei, const int* __restrict__ flag,
                            float* __restrict__ deg) {
    int e = blockIdx.x * 256 + threadIdx.x;
    if (e >= NE) return;
    int d = (*flag) ? (int)((const long long*)ei)[NE + e] : ((const int*)ei)[NE + e];
    atomicAdd(&deg[d], 1.0f);
}

__global__ void rsqrt_k(float* __restrict__ deg) {
    int i = blockIdx.x * 256 + threadIdx.x;
    if (i < NN) deg[i] = rsqrtf(deg[i]);
}

// ---------------- GEMM1: H[N,128] = X[N,128] @ W[128,128] ----------------
// 32 rows/block, 256 threads, thread = (rg 0..7, cg 0..31) computes 4 rows x 4 cols.
// W staged in LDS in two 64-row K-phases (32 KB each); X tile stride-129 padded.
__global__ __launch_bounds__(256) void gemm128_k(const float* __restrict__ X,
                                                 const float* __restrict__ W,
                                                 float* __restrict__ H) {
    __shared__ float4 Ws[64 * 32];   // 32 KB, W rows [kb*64, kb*64+64)
    __shared__ float  Xs[32 * 129];  // 16.5 KB, padded stride kills bank conflicts
    int tid = threadIdx.x;
    long long row0 = (long long)blockIdx.x * 32;

    const float4* X4 = (const float4*)(X + row0 * 128);
#pragma unroll
    for (int i = 0; i < 4; i++) {
        int idx = tid + 256 * i;          // 0..1023 over 32x32 float4 tile
        int r = idx >> 5, c = idx & 31;
        float4 v = X4[idx];
        float* xr = &Xs[r * 129 + c * 4];
        xr[0] = v.x; xr[1] = v.y; xr[2] = v.z; xr[3] = v.w;
    }

    int cg = tid & 31, rg = tid >> 5;
    float4 acc[4];
#pragma unroll
    for (int i = 0; i < 4; i++) acc[i] = make_float4(0.f, 0.f, 0.f, 0.f);

    const float4* W4 = (const float4*)W;  // 128x32 float4
    for (int kb = 0; kb < 2; kb++) {
        __syncthreads();                  // Xs ready (kb=0) / Ws drained (kb=1)
#pragma unroll
        for (int i = 0; i < 8; i++) Ws[tid + 256 * i] = W4[kb * 2048 + tid + 256 * i];
        __syncthreads();
#pragma unroll 4
        for (int kk = 0; kk < 64; kk++) {
            int k = kb * 64 + kk;
            float4 w = Ws[kk * 32 + cg];
#pragma unroll
            for (int i = 0; i < 4; i++) {
                float a = Xs[(rg * 4 + i) * 129 + k];
                acc[i].x = fmaf(a, w.x, acc[i].x);
                acc[i].y = fmaf(a, w.y, acc[i].y);
                acc[i].z = fmaf(a, w.z, acc[i].z);
                acc[i].w = fmaf(a, w.w, acc[i].w);
            }
        }
    }
    float4* H4 = (float4*)(H + row0 * 128);
#pragma unroll
    for (int i = 0; i < 4; i++) H4[(rg * 4 + i) * 32 + cg] = acc[i];
}

// ---------------- GEMM2: H[N,64] = relu(A[N,128]) @ W[128,64] ----------------
__global__ __launch_bounds__(256) void gemm64_relu_k(const float* __restrict__ A,
                                                     const float* __restrict__ W,
                                                     float* __restrict__ H) {
    __shared__ float4 Ws[128 * 16];  // 32 KB (all of W2)
    __shared__ float  Xs[32 * 129];
    int tid = threadIdx.x;
    long long row0 = (long long)blockIdx.x * 32;

    const float4* W4 = (const float4*)W;  // 2048 float4
#pragma unroll
    for (int i = 0; i < 8; i++) Ws[tid + 256 * i] = W4[tid + 256 * i];

    const float4* A4 = (const float4*)(A + row0 * 128);
#pragma unroll
    for (int i = 0; i < 4; i++) {
        int idx = tid + 256 * i;
        int r = idx >> 5, c = idx & 31;
        float4 v = A4[idx];
        float* xr = &Xs[r * 129 + c * 4];
        xr[0] = fmaxf(v.x, 0.f); xr[1] = fmaxf(v.y, 0.f);
        xr[2] = fmaxf(v.z, 0.f); xr[3] = fmaxf(v.w, 0.f);
    }
    __syncthreads();

    int cg = tid & 15, rg = tid >> 4;   // 16 col-groups x 16 row-groups, 2 rows each
    float4 acc[2];
    acc[0] = make_float4(0.f, 0.f, 0.f, 0.f);
    acc[1] = make_float4(0.f, 0.f, 0.f, 0.f);
#pragma unroll 4
    for (int k = 0; k < 128; k++) {
        float4 w = Ws[k * 16 + cg];
#pragma unroll
        for (int i = 0; i < 2; i++) {
            float a = Xs[(rg * 2 + i) * 129 + k];
            acc[i].x = fmaf(a, w.x, acc[i].x);
            acc[i].y = fmaf(a, w.y, acc[i].y);
            acc[i].z = fmaf(a, w.z, acc[i].z);
            acc[i].w = fmaf(a, w.w, acc[i].w);
        }
    }
    float4* H4 = (float4*)(H + row0 * 64);
#pragma unroll
    for (int i = 0; i < 2; i++) H4[(rg * 2 + i) * 16 + cg] = acc[i];
}

// ---------------- init agg = bias + self-loop (non-atomic, pre-scatter) ----------------
// P4 = feature_dim/4. agg[i][:] = b[:] + h[i][:] * dinv[i]^2
template <int P4>
__global__ __launch_bounds__(256) void init_agg_k(const float* __restrict__ h,
                                                  const float* __restrict__ dinv,
                                                  const float* __restrict__ b,
                                                  float* __restrict__ agg) {
    long long gid = (long long)blockIdx.x * 256 + threadIdx.x;
    if (gid >= (long long)NN * P4) return;
    long long i = gid / P4;
    int p = (int)(gid % P4);
    float w = dinv[i]; w *= w;
    float4 v = ((const float4*)h)[gid];
    float4 bb = ((const float4*)b)[p];
    float4 o;
    o.x = fmaf(v.x, w, bb.x); o.y = fmaf(v.y, w, bb.y);
    o.z = fmaf(v.z, w, bb.z); o.w = fmaf(v.w, w, bb.w);
    ((float4*)agg)[gid] = o;
}

// ---------------- edge scatter: agg[dst] += h[src] * dinv[src]*dinv[dst] ----------------
// P4 threads per edge, each handles one float4 of the feature row.
template <int P4>
__global__ __launch_bounds__(256) void edge_agg_k(const void* __restrict__ ei,
                                                  const int* __restrict__ flag,
                                                  const float* __restrict__ dinv,
                                                  const float* __restrict__ h,
                                                  float* __restrict__ agg) {
    long long gid = (long long)blockIdx.x * 256 + threadIdx.x;
    long long e = gid / P4;
    int p = (int)(gid % P4);
    if (e >= NE) return;
    int s, d;
    if (*flag) {
        s = (int)((const long long*)ei)[e];
        d = (int)((const long long*)ei)[NE + e];
    } else {
        s = ((const int*)ei)[e];
        d = ((const int*)ei)[NE + e];
    }
    float w = dinv[s] * dinv[d];
    float4 v = ((const float4*)h)[(long long)s * P4 + p];
    float* o = agg + ((long long)d * P4 + p) * 4;
    atomicAdd(o + 0, v.x * w);
    atomicAdd(o + 1, v.y * w);
    atomicAdd(o + 2, v.z * w);
    atomicAdd(o + 3, v.w * w);
}

// ---------------- launch ----------------
extern "C" void kernel_launch(void* const* d_in, const int* in_sizes, int n_in,
                              void* d_out, int out_size, void* d_ws, size_t ws_size,
                              hipStream_t stream) {
    const float* x  = (const float*)d_in[0];
    const void*  ei = d_in[1];
    const float* W1 = (const float*)d_in[2];
    const float* b1 = (const float*)d_in[3];
    const float* W2 = (const float*)d_in[4];
    const float* b2 = (const float*)d_in[5];
    float* out = (float*)d_out;

    char* ws = (char*)d_ws;
    int*   flag = (int*)ws;                                   // 4 B
    float* dinv = (float*)(ws + 1024);                        // 400 KB
    float* h    = (float*)(ws + (1ll << 20));                 // 51.2 MB
    float* agg1 = (float*)(ws + (1ll << 20) + (52ll << 20));  // 51.2 MB
    float* h2   = h;  // reuse: h dead after layer-1 scatter

    detect_i64_k<<<1, 64, 0, stream>>>((const unsigned*)ei, flag);
    init_deg_k<<<(NN + 255) / 256, 256, 0, stream>>>(dinv);
    count_deg_k<<<(NE + 255) / 256, 256, 0, stream>>>(ei, flag, dinv);
    rsqrt_k<<<(NN + 255) / 256, 256, 0, stream>>>(dinv);

    // Layer 1
    gemm128_k<<<NN / 32, 256, 0, stream>>>(x, W1, h);
    {
        long long t = (long long)NN * 32;
        init_agg_k<32><<<(unsigned)((t + 255) / 256), 256, 0, stream>>>(h, dinv, b1, agg1);
        long long t2 = (long long)NE * 32;
        edge_agg_k<32><<<(unsigned)((t2 + 255) / 256), 256, 0, stream>>>(ei, flag, dinv, h, agg1);
    }

    // Layer 2
    gemm64_relu_k<<<NN / 32, 256, 0, stream>>>(agg1, W2, h2);
    {
        long long t = (long long)NN * 16;
        init_agg_k<16><<<(unsigned)((t + 255) / 256), 256, 0, stream>>>(h2, dinv, b2, out);
        long long t2 = (long long)NE * 16;
        edge_agg_k<16><<<(unsigned)((t2 + 255) / 256), 256, 0, stream>>>(ei, flag, dinv, h2, out);
    }
}

// Round 2
// 588.235 us; speedup vs baseline: 7.3451x; 7.3451x over previous
//
#include <hip/hip_runtime.h>

#define NN 100000
#define NE 1600000
#define NBLK_SCAN ((NN + 255) / 256)   // 391

// ---------------- dtype detector: edge_index int64 vs int32 ----------------
__global__ void detect_i64_k(const unsigned* __restrict__ ei, int* __restrict__ flag) {
    unsigned w = ei[2 * threadIdx.x + 1];
    unsigned long long b = __ballot(w == 0u);
    if (threadIdx.x == 0) *flag = (b == 0xFFFFFFFFFFFFFFFFull) ? 1 : 0;
}

__device__ __forceinline__ int load_node(const void* ei, int i64, long long idx) {
    return i64 ? (int)((const long long*)ei)[idx] : ((const int*)ei)[idx];
}

// ---------------- degree count (int atomics, ~16 avg contention) ----------------
__global__ void count_deg_k(const void* __restrict__ ei, const int* __restrict__ flag,
                            int* __restrict__ cnt) {
    int e = blockIdx.x * 256 + threadIdx.x;
    if (e >= NE) return;
    int d = load_node(ei, *flag, (long long)NE + e);
    atomicAdd(&cnt[d], 1);
}

__global__ void dinv_k(const int* __restrict__ cnt, float* __restrict__ dinv) {
    int i = blockIdx.x * 256 + threadIdx.x;
    if (i < NN) dinv[i] = rsqrtf((float)(cnt[i] + 1));   // +1 self-loop
}

// ---------------- hierarchical exclusive scan: cnt -> rowptr ----------------
__global__ void scan1_k(const int* __restrict__ cnt, int* __restrict__ rowptr,
                        int* __restrict__ bsum) {
    __shared__ int s[256];
    int t = threadIdx.x;
    int i = blockIdx.x * 256 + t;
    int v = (i < NN) ? cnt[i] : 0;
    s[t] = v;
    __syncthreads();
    for (int off = 1; off < 256; off <<= 1) {
        int add = (t >= off) ? s[t - off] : 0;
        __syncthreads();
        s[t] += add;
        __syncthreads();
    }
    if (i < NN) rowptr[i] = s[t] - v;              // block-local exclusive
    if (t == 255) bsum[blockIdx.x] = s[255];       // block total
}

__global__ void scan2_k(int* __restrict__ bsum) {   // 1 block, 512 threads
    __shared__ int s[512];
    int t = threadIdx.x;
    int v = (t < NBLK_SCAN) ? bsum[t] : 0;
    s[t] = v;
    __syncthreads();
    for (int off = 1; off < 512; off <<= 1) {
        int add = (t >= off) ? s[t - off] : 0;
        __syncthreads();
        s[t] += add;
        __syncthreads();
    }
    if (t < NBLK_SCAN) bsum[t] = s[t] - v;          // exclusive block offsets
}

__global__ void scan3_k(int* __restrict__ rowptr, const int* __restrict__ bsum) {
    int i = blockIdx.x * 256 + threadIdx.x;
    if (i < NN) rowptr[i] += bsum[blockIdx.x];
    if (i == 0) rowptr[NN] = NE;
}

// ---------------- CSR bucket fill ----------------
__global__ void fill_k(const void* __restrict__ ei, const int* __restrict__ flag,
                       const int* __restrict__ rowptr, int* __restrict__ fillpos,
                       int* __restrict__ col) {
    int e = blockIdx.x * 256 + threadIdx.x;
    if (e >= NE) return;
    int i64 = *flag;
    int s = load_node(ei, i64, e);
    int d = load_node(ei, i64, (long long)NE + e);
    int pos = atomicAdd(&fillpos[d], 1);
    col[rowptr[d] + pos] = s;
}

// ---------------- GEMM: C[N,64] = A[N,128] @ Wsub[128,64] ----------------
// 32 rows/block, 256 threads; thread = (rg 0..15, cg 0..15): 2 rows x 1 float4.
// Wsub = W[:, woff4*4 : woff4*4+64] with row stride wstride4 (in float4 units).
__global__ __launch_bounds__(256) void gemm64_k(const float* __restrict__ A,
                                                const float* __restrict__ W,
                                                int wstride4, int woff4,
                                                float* __restrict__ C) {
    __shared__ float4 Ws[128 * 16];  // 32 KB
    __shared__ float  Xs[32 * 129];  // 16.5 KB, padded stride
    int tid = threadIdx.x;
    long long row0 = (long long)blockIdx.x * 32;

    const float4* W4 = (const float4*)W;
#pragma unroll
    for (int i = 0; i < 8; i++) {
        int idx = tid + 256 * i;              // 0..2047
        int r = idx >> 4, c = idx & 15;
        Ws[idx] = W4[(long long)r * wstride4 + woff4 + c];
    }

    const float4* A4 = (const float4*)(A + row0 * 128);
#pragma unroll
    for (int i = 0; i < 4; i++) {
        int idx = tid + 256 * i;              // 0..1023 over 32x32 float4 tile
        int r = idx >> 5, c = idx & 31;
        float4 v = A4[idx];
        float* xr = &Xs[r * 129 + c * 4];
        xr[0] = v.x; xr[1] = v.y; xr[2] = v.z; xr[3] = v.w;
    }
    __syncthreads();

    int cg = tid & 15, rg = tid >> 4;
    float4 acc[2];
    acc[0] = make_float4(0.f, 0.f, 0.f, 0.f);
    acc[1] = make_float4(0.f, 0.f, 0.f, 0.f);
#pragma unroll 4
    for (int k = 0; k < 128; k++) {
        float4 w = Ws[k * 16 + cg];
#pragma unroll
        for (int i = 0; i < 2; i++) {
            float a = Xs[(rg * 2 + i) * 129 + k];
            acc[i].x = fmaf(a, w.x, acc[i].x);
            acc[i].y = fmaf(a, w.y, acc[i].y);
            acc[i].z = fmaf(a, w.z, acc[i].z);
            acc[i].w = fmaf(a, w.w, acc[i].w);
        }
    }
    float4* C4 = (float4*)(C + row0 * 64);
#pragma unroll
    for (int i = 0; i < 2; i++) C4[(rg * 2 + i) * 16 + cg] = acc[i];
}

// ---------------- atomic-free pull aggregation over 64 features ----------------
// out[node, :64 @ ooff4/ostride4] = relu?( b + h[node]*dinv^2 + sum_e h[src]*dinv[src]*dinv[node] )
// 16 lanes per node (one float4 each), 16 nodes per 256-block.
template <bool RELU>
__global__ __launch_bounds__(256) void pull64_k(const int* __restrict__ col,
                                                const int* __restrict__ rowptr,
                                                const float* __restrict__ dinv,
                                                const float* __restrict__ h,
                                                const float* __restrict__ bias,
                                                float* __restrict__ out,
                                                int ostride4, int ooff4) {
    int tid = threadIdx.x;
    int node = blockIdx.x * 16 + (tid >> 4);
    int lane = tid & 15;
    if (node >= NN) return;

    const float4* h4 = (const float4*)h;
    float di = dinv[node];
    float w0 = di * di;
    float4 hv = h4[(long long)node * 16 + lane];
    float4 acc = make_float4(hv.x * w0, hv.y * w0, hv.z * w0, hv.w * w0);

    int beg = rowptr[node], end = rowptr[node + 1];
    for (int j = beg; j < end; j++) {
        int s = col[j];                       // broadcast across 16 lanes
        float w = dinv[s] * di;               // broadcast
        float4 v = h4[(long long)s * 16 + lane];
        acc.x = fmaf(v.x, w, acc.x);
        acc.y = fmaf(v.y, w, acc.y);
        acc.z = fmaf(v.z, w, acc.z);
        acc.w = fmaf(v.w, w, acc.w);
    }
    float4 bb = ((const float4*)bias)[lane];
    acc.x += bb.x; acc.y += bb.y; acc.z += bb.z; acc.w += bb.w;
    if (RELU) {
        acc.x = fmaxf(acc.x, 0.f); acc.y = fmaxf(acc.y, 0.f);
        acc.z = fmaxf(acc.z, 0.f); acc.w = fmaxf(acc.w, 0.f);
    }
    ((float4*)out)[(long long)node * ostride4 + ooff4 + lane] = acc;
}

// ---------------- launch ----------------
extern "C" void kernel_launch(void* const* d_in, const int* in_sizes, int n_in,
                              void* d_out, int out_size, void* d_ws, size_t ws_size,
                              hipStream_t stream) {
    const float* x  = (const float*)d_in[0];
    const void*  ei = d_in[1];
    const float* W1 = (const float*)d_in[2];
    const float* b1 = (const float*)d_in[3];
    const float* W2 = (const float*)d_in[4];
    const float* b2 = (const float*)d_in[5];
    float* out = (float*)d_out;

    char* ws = (char*)d_ws;
    int*   flag   = (int*)ws;                        // 4 B
    int*   cnt    = (int*)(ws + 4096);               // 400 KB (reused as fillpos)
    float* dinv   = (float*)(ws + 0x80000);          // 400 KB
    int*   rowptr = (int*)(ws + 0x100000);           // 400 KB + 4
    int*   bsum   = (int*)(ws + 0x180000);           // 2 KB
    int*   col    = (int*)(ws + 0x200000);           // 6.4 MB
    float* hh     = (float*)(ws + 0x900000);         // 25.6 MB  (per-half h / h2)
    float* agg1   = (float*)(ws + 0x2200000);        // 51.2 MB  (ends ~82.8 MB)

    // ---- CSR + norm build ----
    hipMemsetAsync(cnt, 0, NN * sizeof(int), stream);
    detect_i64_k<<<1, 64, 0, stream>>>((const unsigned*)ei, flag);
    count_deg_k<<<(NE + 255) / 256, 256, 0, stream>>>(ei, flag, cnt);
    dinv_k<<<NBLK_SCAN, 256, 0, stream>>>(cnt, dinv);
    scan1_k<<<NBLK_SCAN, 256, 0, stream>>>(cnt, rowptr, bsum);
    scan2_k<<<1, 512, 0, stream>>>(bsum);
    scan3_k<<<NBLK_SCAN, 256, 0, stream>>>(rowptr, bsum);
    hipMemsetAsync(cnt, 0, NN * sizeof(int), stream);     // cnt -> fillpos
    fill_k<<<(NE + 255) / 256, 256, 0, stream>>>(ei, flag, rowptr, cnt, col);

    // ---- Layer 1, feature halves (bias+relu fused into pull epilogue) ----
    for (int half = 0; half < 2; half++) {
        gemm64_k<<<NN / 32, 256, 0, stream>>>(x, W1, 32, half * 16, hh);
        pull64_k<true><<<NN / 16, 256, 0, stream>>>(col, rowptr, dinv, hh,
                                                    b1 + half * 64, agg1, 32, half * 16);
    }

    // ---- Layer 2: transform-first, pull into d_out ----
    gemm64_k<<<NN / 32, 256, 0, stream>>>(agg1, W2, 16, 0, hh);
    pull64_k<false><<<NN / 16, 256, 0, stream>>>(col, rowptr, dinv, hh, b2, out, 16, 0);
}

// Round 3
// 487.804 us; speedup vs baseline: 8.8573x; 1.2059x over previous
//
#include <hip/hip_runtime.h>

#define NN 100000
#define NE 1600000
#define ELLW 48
#define NBLK_SCAN ((NN + 255) / 256)   // 391

// ---------------- dtype detector: edge_index int64 vs int32 ----------------
__global__ void detect_i64_k(const unsigned* __restrict__ ei, int* __restrict__ flag) {
    unsigned w = ei[2 * threadIdx.x + 1];
    unsigned long long b = __ballot(w == 0u);
    if (threadIdx.x == 0) *flag = (b == 0xFFFFFFFFFFFFFFFFull) ? 1 : 0;
}

__device__ __forceinline__ int load_node(const void* ei, int i64, long long idx) {
    return i64 ? (int)((const long long*)ei)[idx] : ((const int*)ei)[idx];
}

__global__ void dinv_k(const int* __restrict__ cnt, float* __restrict__ dinv) {
    int i = blockIdx.x * 256 + threadIdx.x;
    if (i < NN) dinv[i] = rsqrtf((float)(cnt[i] + 1));   // +1 self-loop
}

// =======================  WIDE PATH (ELL)  =======================

// one-pass ELL adjacency build: ell[d*ELLW + pos] = s
__global__ void ell_fill_k(const void* __restrict__ ei, const int* __restrict__ flag,
                           int* __restrict__ cnt, int* __restrict__ ell) {
    int e = blockIdx.x * 256 + threadIdx.x;
    if (e >= NE) return;
    int i64 = *flag;
    int s = load_node(ei, i64, e);
    int d = load_node(ei, i64, (long long)NE + e);
    int pos = atomicAdd(&cnt[d], 1);
    if (pos < ELLW) ell[(long long)d * ELLW + pos] = s;
}

// ELL pull: P4 lanes per node (one float4 each). Feature dim = 4*P4.
template <bool RELU, int P4>
__global__ __launch_bounds__(256) void pull_ell_k(const int* __restrict__ ell,
                                                  const int* __restrict__ cnt,
                                                  const float* __restrict__ dinv,
                                                  const float* __restrict__ h,
                                                  const float* __restrict__ bias,
                                                  float* __restrict__ out) {
    int tid = threadIdx.x;
    int node = blockIdx.x * (256 / P4) + tid / P4;
    int lane = tid % P4;
    if (node >= NN) return;

    const float4* h4 = (const float4*)h;
    float di = dinv[node];
    float w0 = di * di;
    float4 hv = h4[(long long)node * P4 + lane];
    float4 acc0 = make_float4(hv.x * w0, hv.y * w0, hv.z * w0, hv.w * w0);
    float4 acc1 = make_float4(0.f, 0.f, 0.f, 0.f);

    int deg = cnt[node];
    const int* row = ell + (long long)node * ELLW;
    int j = 0;
    for (; j + 1 < deg; j += 2) {
        int s0 = row[j], s1 = row[j + 1];
        float ww0 = dinv[s0] * di, ww1 = dinv[s1] * di;
        float4 v0 = h4[(long long)s0 * P4 + lane];
        float4 v1 = h4[(long long)s1 * P4 + lane];
        acc0.x = fmaf(v0.x, ww0, acc0.x); acc0.y = fmaf(v0.y, ww0, acc0.y);
        acc0.z = fmaf(v0.z, ww0, acc0.z); acc0.w = fmaf(v0.w, ww0, acc0.w);
        acc1.x = fmaf(v1.x, ww1, acc1.x); acc1.y = fmaf(v1.y, ww1, acc1.y);
        acc1.z = fmaf(v1.z, ww1, acc1.z); acc1.w = fmaf(v1.w, ww1, acc1.w);
    }
    if (j < deg) {
        int s0 = row[j];
        float ww0 = dinv[s0] * di;
        float4 v0 = h4[(long long)s0 * P4 + lane];
        acc0.x = fmaf(v0.x, ww0, acc0.x); acc0.y = fmaf(v0.y, ww0, acc0.y);
        acc0.z = fmaf(v0.z, ww0, acc0.z); acc0.w = fmaf(v0.w, ww0, acc0.w);
    }
    float4 bb = ((const float4*)bias)[lane];
    acc0.x += acc1.x + bb.x; acc0.y += acc1.y + bb.y;
    acc0.z += acc1.z + bb.z; acc0.w += acc1.w + bb.w;
    if (RELU) {
        acc0.x = fmaxf(acc0.x, 0.f); acc0.y = fmaxf(acc0.y, 0.f);
        acc0.z = fmaxf(acc0.z, 0.f); acc0.w = fmaxf(acc0.w, 0.f);
    }
    ((float4*)out)[(long long)node * P4 + lane] = acc0;
}

// GEMM1: H[N,128] = X[N,128] @ W[128,128]; 32 rows/block (proven round 1)
__global__ __launch_bounds__(256) void gemm128_k(const float* __restrict__ X,
                                                 const float* __restrict__ W,
                                                 float* __restrict__ H) {
    __shared__ float4 Ws[64 * 32];
    __shared__ float  Xs[32 * 129];
    int tid = threadIdx.x;
    long long row0 = (long long)blockIdx.x * 32;

    const float4* X4 = (const float4*)(X + row0 * 128);
#pragma unroll
    for (int i = 0; i < 4; i++) {
        int idx = tid + 256 * i;
        int r = idx >> 5, c = idx & 31;
        float4 v = X4[idx];
        float* xr = &Xs[r * 129 + c * 4];
        xr[0] = v.x; xr[1] = v.y; xr[2] = v.z; xr[3] = v.w;
    }

    int cg = tid & 31, rg = tid >> 5;
    float4 acc[4];
#pragma unroll
    for (int i = 0; i < 4; i++) acc[i] = make_float4(0.f, 0.f, 0.f, 0.f);

    const float4* W4 = (const float4*)W;
    for (int kb = 0; kb < 2; kb++) {
        __syncthreads();
#pragma unroll
        for (int i = 0; i < 8; i++) Ws[tid + 256 * i] = W4[kb * 2048 + tid + 256 * i];
        __syncthreads();
#pragma unroll 4
        for (int kk = 0; kk < 64; kk++) {
            int k = kb * 64 + kk;
            float4 w = Ws[kk * 32 + cg];
#pragma unroll
            for (int i = 0; i < 4; i++) {
                float a = Xs[(rg * 4 + i) * 129 + k];
                acc[i].x = fmaf(a, w.x, acc[i].x);
                acc[i].y = fmaf(a, w.y, acc[i].y);
                acc[i].z = fmaf(a, w.z, acc[i].z);
                acc[i].w = fmaf(a, w.w, acc[i].w);
            }
        }
    }
    float4* H4 = (float4*)(H + row0 * 128);
#pragma unroll
    for (int i = 0; i < 4; i++) H4[(rg * 4 + i) * 32 + cg] = acc[i];
}

// GEMM: C[N,64] = A[N,128] @ Wsub[128,64] (Wsub = W[:, woff4*4 .. +64], stride wstride4)
__global__ __launch_bounds__(256) void gemm64_k(const float* __restrict__ A,
                                                const float* __restrict__ W,
                                                int wstride4, int woff4,
                                                float* __restrict__ C) {
    __shared__ float4 Ws[128 * 16];
    __shared__ float  Xs[32 * 129];
    int tid = threadIdx.x;
    long long row0 = (long long)blockIdx.x * 32;

    const float4* W4 = (const float4*)W;
#pragma unroll
    for (int i = 0; i < 8; i++) {
        int idx = tid + 256 * i;
        int r = idx >> 4, c = idx & 15;
        Ws[idx] = W4[(long long)r * wstride4 + woff4 + c];
    }

    const float4* A4 = (const float4*)(A + row0 * 128);
#pragma unroll
    for (int i = 0; i < 4; i++) {
        int idx = tid + 256 * i;
        int r = idx >> 5, c = idx & 31;
        float4 v = A4[idx];
        float* xr = &Xs[r * 129 + c * 4];
        xr[0] = v.x; xr[1] = v.y; xr[2] = v.z; xr[3] = v.w;
    }
    __syncthreads();

    int cg = tid & 15, rg = tid >> 4;
    float4 acc[2];
    acc[0] = make_float4(0.f, 0.f, 0.f, 0.f);
    acc[1] = make_float4(0.f, 0.f, 0.f, 0.f);
#pragma unroll 4
    for (int k = 0; k < 128; k++) {
        float4 w = Ws[k * 16 + cg];
#pragma unroll
        for (int i = 0; i < 2; i++) {
            float a = Xs[(rg * 2 + i) * 129 + k];
            acc[i].x = fmaf(a, w.x, acc[i].x);
            acc[i].y = fmaf(a, w.y, acc[i].y);
            acc[i].z = fmaf(a, w.z, acc[i].z);
            acc[i].w = fmaf(a, w.w, acc[i].w);
        }
    }
    float4* C4 = (float4*)(C + row0 * 64);
#pragma unroll
    for (int i = 0; i < 2; i++) C4[(rg * 2 + i) * 16 + cg] = acc[i];
}

// =======================  NARROW FALLBACK (round-2 CSR, proven ≤83 MB)  =======================

__global__ void count_deg_k(const void* __restrict__ ei, const int* __restrict__ flag,
                            int* __restrict__ cnt) {
    int e = blockIdx.x * 256 + threadIdx.x;
    if (e >= NE) return;
    int d = load_node(ei, *flag, (long long)NE + e);
    atomicAdd(&cnt[d], 1);
}

__global__ void scan1_k(const int* __restrict__ cnt, int* __restrict__ rowptr,
                        int* __restrict__ bsum) {
    __shared__ int s[256];
    int t = threadIdx.x;
    int i = blockIdx.x * 256 + t;
    int v = (i < NN) ? cnt[i] : 0;
    s[t] = v;
    __syncthreads();
    for (int off = 1; off < 256; off <<= 1) {
        int add = (t >= off) ? s[t - off] : 0;
        __syncthreads();
        s[t] += add;
        __syncthreads();
    }
    if (i < NN) rowptr[i] = s[t] - v;
    if (t == 255) bsum[blockIdx.x] = s[255];
}

__global__ void scan2_k(int* __restrict__ bsum) {
    __shared__ int s[512];
    int t = threadIdx.x;
    int v = (t < NBLK_SCAN) ? bsum[t] : 0;
    s[t] = v;
    __syncthreads();
    for (int off = 1; off < 512; off <<= 1) {
        int add = (t >= off) ? s[t - off] : 0;
        __syncthreads();
        s[t] += add;
        __syncthreads();
    }
    if (t < NBLK_SCAN) bsum[t] = s[t] - v;
}

__global__ void scan3_k(int* __restrict__ rowptr, const int* __restrict__ bsum) {
    int i = blockIdx.x * 256 + threadIdx.x;
    if (i < NN) rowptr[i] += bsum[blockIdx.x];
    if (i == 0) rowptr[NN] = NE;
}

__global__ void fill_k(const void* __restrict__ ei, const int* __restrict__ flag,
                       const int* __restrict__ rowptr, int* __restrict__ fillpos,
                       int* __restrict__ col) {
    int e = blockIdx.x * 256 + threadIdx.x;
    if (e >= NE) return;
    int i64 = *flag;
    int s = load_node(ei, i64, e);
    int d = load_node(ei, i64, (long long)NE + e);
    int pos = atomicAdd(&fillpos[d], 1);
    col[rowptr[d] + pos] = s;
}

template <bool RELU>
__global__ __launch_bounds__(256) void pull64_k(const int* __restrict__ col,
                                                const int* __restrict__ rowptr,
                                                const float* __restrict__ dinv,
                                                const float* __restrict__ h,
                                                const float* __restrict__ bias,
                                                float* __restrict__ out,
                                                int ostride4, int ooff4) {
    int tid = threadIdx.x;
    int node = blockIdx.x * 16 + (tid >> 4);
    int lane = tid & 15;
    if (node >= NN) return;

    const float4* h4 = (const float4*)h;
    float di = dinv[node];
    float w0 = di * di;
    float4 hv = h4[(long long)node * 16 + lane];
    float4 acc = make_float4(hv.x * w0, hv.y * w0, hv.z * w0, hv.w * w0);

    int beg = rowptr[node], end = rowptr[node + 1];
    for (int j = beg; j < end; j++) {
        int s = col[j];
        float w = dinv[s] * di;
        float4 v = h4[(long long)s * 16 + lane];
        acc.x = fmaf(v.x, w, acc.x);
        acc.y = fmaf(v.y, w, acc.y);
        acc.z = fmaf(v.z, w, acc.z);
        acc.w = fmaf(v.w, w, acc.w);
    }
    float4 bb = ((const float4*)bias)[lane];
    acc.x += bb.x; acc.y += bb.y; acc.z += bb.z; acc.w += bb.w;
    if (RELU) {
        acc.x = fmaxf(acc.x, 0.f); acc.y = fmaxf(acc.y, 0.f);
        acc.z = fmaxf(acc.z, 0.f); acc.w = fmaxf(acc.w, 0.f);
    }
    ((float4*)out)[(long long)node * ostride4 + ooff4 + lane] = acc;
}

// ---------------- launch ----------------
extern "C" void kernel_launch(void* const* d_in, const int* in_sizes, int n_in,
                              void* d_out, int out_size, void* d_ws, size_t ws_size,
                              hipStream_t stream) {
    const float* x  = (const float*)d_in[0];
    const void*  ei = d_in[1];
    const float* W1 = (const float*)d_in[2];
    const float* b1 = (const float*)d_in[3];
    const float* W2 = (const float*)d_in[4];
    const float* b2 = (const float*)d_in[5];
    float* out = (float*)d_out;
    char* ws = (char*)d_ws;

    if (ws_size >= 125000000ull) {
        // ---------- WIDE ELL PATH ----------
        int*   flag = (int*)ws;                       // 4 B
        int*   cnt  = (int*)(ws + 0x1000);            // 400 KB
        float* dinv = (float*)(ws + 0x70000);         // 400 KB
        int*   ell  = (int*)(ws + 0x200000);          // 19.2 MB
        float* h    = (float*)(ws + 0x1500000);       // 51.2 MB
        float* agg1 = (float*)(ws + 0x4600000);       // 51.2 MB (ends ~124.6 MB)
        float* h2   = h;                              // reuse after layer-1 pull

        hipMemsetAsync(cnt, 0, NN * sizeof(int), stream);
        detect_i64_k<<<1, 64, 0, stream>>>((const unsigned*)ei, flag);
        ell_fill_k<<<(NE + 255) / 256, 256, 0, stream>>>(ei, flag, cnt, ell);
        dinv_k<<<NBLK_SCAN, 256, 0, stream>>>(cnt, dinv);

        gemm128_k<<<NN / 32, 256, 0, stream>>>(x, W1, h);
        pull_ell_k<true, 32><<<(NN + 7) / 8, 256, 0, stream>>>(ell, cnt, dinv, h, b1, agg1);

        gemm64_k<<<NN / 32, 256, 0, stream>>>(agg1, W2, 16, 0, h2);
        pull_ell_k<false, 16><<<(NN + 15) / 16, 256, 0, stream>>>(ell, cnt, dinv, h2, b2, out);
    } else {
        // ---------- NARROW CSR FALLBACK (proven round-2) ----------
        int*   flag   = (int*)ws;
        int*   cnt    = (int*)(ws + 4096);
        float* dinv   = (float*)(ws + 0x80000);
        int*   rowptr = (int*)(ws + 0x100000);
        int*   bsum   = (int*)(ws + 0x180000);
        int*   col    = (int*)(ws + 0x200000);
        float* hh     = (float*)(ws + 0x900000);
        float* agg1   = (float*)(ws + 0x2200000);

        hipMemsetAsync(cnt, 0, NN * sizeof(int), stream);
        detect_i64_k<<<1, 64, 0, stream>>>((const unsigned*)ei, flag);
        count_deg_k<<<(NE + 255) / 256, 256, 0, stream>>>(ei, flag, cnt);
        dinv_k<<<NBLK_SCAN, 256, 0, stream>>>(cnt, dinv);
        scan1_k<<<NBLK_SCAN, 256, 0, stream>>>(cnt, rowptr, bsum);
        scan2_k<<<1, 512, 0, stream>>>(bsum);
        scan3_k<<<NBLK_SCAN, 256, 0, stream>>>(rowptr, bsum);
        hipMemsetAsync(cnt, 0, NN * sizeof(int), stream);
        fill_k<<<(NE + 255) / 256, 256, 0, stream>>>(ei, flag, rowptr, cnt, col);

        for (int half = 0; half < 2; half++) {
            gemm64_k<<<NN / 32, 256, 0, stream>>>(x, W1, 32, half * 16, hh);
            pull64_k<true><<<NN / 16, 256, 0, stream>>>(col, rowptr, dinv, hh,
                                                        b1 + half * 64, agg1, 32, half * 16);
        }
        gemm64_k<<<NN / 32, 256, 0, stream>>>(agg1, W2, 16, 0, hh);
        pull64_k<false><<<NN / 16, 256, 0, stream>>>(col, rowptr, dinv, hh, b2, out, 16, 0);
    }
}